// Round 2
// baseline (231.558 us; speedup 1.0000x reference)
//
#include <hip/hip_runtime.h>

// y[e] = W2 . relu(W1 . concat(z[src[e]], z[dst[e]]) + b1) + b2
// N=50000, D=128, H=512, E=500000. 131 GFLOP in GEMM1.
// R9: persistent blocks + B-in-registers. R8 re-read the whole 256KB w1s
// from L2 for EVERY 64-edge block (2 GB of L2 traffic ~= 4.6K cyc/block,
// the dominant term; MFMA only 1.2K). W1 == 8 waves x 128 VGPR, so a
// persistent 512-thread block (grid=512, ~15 tiles each) loads B once into
// regs and loops over edge tiles. Loop is then LDS-BW-bound (~2.6K cyc/tile):
//  - A gather via global_load_lds (async, no staging regs), double-buffered,
//    counted s_waitcnt vmcnt(4) so prefetch stays in flight across barriers
//  - LDS layout: linear [64][256] bf16, 16B-slot XOR swizzle slot^=(row&7);
//    swizzle folded into the per-lane GATHER SOURCE address (linear LDS dest,
//    rule: source-permute == read-permute), conflict-free ds_read_b128
//  - vmcnt discipline: per wave per iter exactly 4 gathers + 4 idx loads
//    (+1 store, wave 0, always NEWEST in the queue); idx loads pinned after
//    gather-issue by memory-clobber fences so vmcnt(4) always completes
//    exactly the 4 gathers.
// VGPR budget: breg 128 + acc 64 + ival/w2/b1/addr ~40 + transients ~=240
// -> launch_bounds(512,2) (256 cap), 2 waves/SIMD, 1 block/CU.

typedef __bf16 bf16x8 __attribute__((ext_vector_type(8)));
typedef float f32x4 __attribute__((ext_vector_type(4)));

__device__ __forceinline__ unsigned short f2b(float f) {
    unsigned int u = __float_as_uint(f);
    u = (u + 0x7fffu + ((u >> 16) & 1u)) >> 16;   // RNE
    return (unsigned short)u;
}

__device__ __forceinline__ void gload_lds16(const unsigned short* g, unsigned short* l) {
    __builtin_amdgcn_global_load_lds(
        (const __attribute__((address_space(1))) unsigned int*)g,
        (__attribute__((address_space(3))) unsigned int*)l, 16, 0, 0);
}

// zb: z as bf16 [N][128].  w1s: W1 swizzled to MFMA-B fragment order:
// w1s[(hblk*8 + kc)*512 + lane*8 + t] = bf16(W1[hblk*16 + (lane&15)][kc*32 + (lane>>4)*8 + t])
__global__ void prep_kernel(const float* __restrict__ z, const float* __restrict__ W1,
                            unsigned short* __restrict__ zb, unsigned short* __restrict__ w1s,
                            int nz4) {
    int stride = gridDim.x * blockDim.x;
    const int nw = 256 * 64;   // (hblk*8+kc) x lane
    const int total = nz4 + nw;
    for (int idx = blockIdx.x * blockDim.x + threadIdx.x; idx < total; idx += stride) {
        if (idx < nz4) {
            float4 v = ((const float4*)z)[idx];
            ushort4 o;
            o.x = f2b(v.x); o.y = f2b(v.y); o.z = f2b(v.z); o.w = f2b(v.w);
            ((ushort4*)zb)[idx] = o;
        } else {
            int u = idx - nz4;            // 0..16383
            int lane = u & 63;
            int blk  = u >> 6;            // hblk*8 + kc
            int h  = (blk >> 3) * 16 + (lane & 15);
            int kb = (blk & 7) * 32 + (lane >> 4) * 8;
            const float* src = W1 + h * 256 + kb;
            ushort4 o0, o1;
            float4 v0 = *(const float4*)(src);
            float4 v1 = *(const float4*)(src + 4);
            o0.x = f2b(v0.x); o0.y = f2b(v0.y); o0.z = f2b(v0.z); o0.w = f2b(v0.w);
            o1.x = f2b(v1.x); o1.y = f2b(v1.y); o1.z = f2b(v1.z); o1.w = f2b(v1.w);
            ushort4* dst = (ushort4*)(w1s + u * 8);
            dst[0] = o0; dst[1] = o1;
        }
    }
}

__global__ __launch_bounds__(512, 2)
void edge_mlp_kernel(const int* __restrict__ ei, const unsigned short* __restrict__ zb,
                     const unsigned short* __restrict__ w1s,
                     const float* __restrict__ b1, const float* __restrict__ W2,
                     const float* __restrict__ b2p, float* __restrict__ out,
                     int E, int ntiles) {
    // linear (unpadded) A tiles, double-buffered; XOR-swizzled 16B slots
    __shared__ unsigned short ldsA[2][64 * 256];  // 2 x 32 KB
    __shared__ float ldsY[512];                   // 2 KB partial-y exchange

    const int tid  = threadIdx.x;
    const int lane = tid & 63;
    const int w    = tid >> 6;        // 0..7 : 64-h slice of H=512
    const int l15  = lane & 15;
    const int l4   = lane >> 4;
    const int G    = gridDim.x;

    const int t0 = blockIdx.x;
    if (t0 >= ntiles) return;

    // ---- persistent B: wave w holds hblk w*4..w*4+3, full K, in regs ----
    uint4 breg[4][8];                 // 128 VGPR
    #pragma unroll
    for (int j = 0; j < 4; ++j)
        #pragma unroll
        for (int kc = 0; kc < 8; ++kc)
            breg[j][kc] = *(const uint4*)(w1s + (((w * 4 + j) * 8 + kc) << 9) + lane * 8);

    float w2v[4], b1v[4];
    #pragma unroll
    for (int j = 0; j < 4; ++j) {
        int h = (w * 4 + j) * 16 + l15;
        w2v[j] = W2[h];
        b1v[j] = b1[h];
    }
    const float b2v = b2p[0];

    // gather geometry: instr it covers rows m0=w*8+it*2 (+rsub), lane L writes
    // LDS (row, slot'=L&31); that slot' holds global k-slot s = slot'^(row&7),
    // side = bit4 of slot (untouched by 3-bit XOR), k_local = (s&15)*8.
    const int side = (lane >> 4) & 1;
    const int rsub = lane >> 5;
    const int swz  = l15 & 7;         // read-side XOR: row&7 == l15&7

    asm volatile("s_waitcnt vmcnt(0)" ::: "memory");   // drain preloads: clean vmcnt base

    // ---- prologue: idx(T0) -> gather(T0) -> idx(T1) ----
    int ival[4];
    #pragma unroll
    for (int it = 0; it < 4; ++it) {
        int e = t0 * 64 + w * 8 + it * 2 + rsub;
        e = (e < E) ? e : (E - 1);
        ival[it] = ei[side * E + e];
    }
    #pragma unroll
    for (int it = 0; it < 4; ++it) {   // compiler waits ival before addr use
        int s15 = l15 ^ ((it * 2 + rsub) & 7);
        gload_lds16(zb + (ival[it] << 7) + (s15 << 3),
                    &ldsA[0][(w * 8 + it * 2) << 8]);
    }
    asm volatile("" ::: "memory");     // pin: idx(T1) must stay AFTER gathers
    {
        int t1 = t0 + G;
        #pragma unroll
        for (int it = 0; it < 4; ++it) {
            int e = t1 * 64 + w * 8 + it * 2 + rsub;
            e = (e < E) ? e : (E - 1);
            ival[it] = ei[side * E + e];
        }
    }

    int cur = 0;
    for (int t = t0; t < ntiles; t += G) {
        // wait own 4 gathers (oldest in queue; idx/store are newer), rendezvous
        asm volatile("s_waitcnt vmcnt(4)" ::: "memory");
        __builtin_amdgcn_s_barrier();
        asm volatile("" ::: "memory");

        const unsigned short* bufc = &ldsA[cur][0];
        unsigned short* bufn = &ldsA[cur ^ 1][0];

        f32x4 acc[4][4];
        #pragma unroll
        for (int i = 0; i < 4; i++)
            #pragma unroll
            for (int j = 0; j < 4; j++) acc[i][j] = (f32x4){0.f, 0.f, 0.f, 0.f};

        #pragma unroll
        for (int kc = 0; kc < 4; ++kc) {
            bf16x8 a[4];
            #pragma unroll
            for (int i = 0; i < 4; ++i)
                a[i] = *(const bf16x8*)&bufc[((l15 + 16 * i) << 8) + ((((kc << 2) + l4) ^ swz) << 3)];
            #pragma unroll
            for (int i = 0; i < 4; ++i)
                #pragma unroll
                for (int j = 0; j < 4; ++j)
                    acc[i][j] = __builtin_amdgcn_mfma_f32_16x16x32_bf16(
                        a[i], *(const bf16x8*)&breg[j][kc], acc[i][j], 0, 0, 0);
        }

        // issue next tile's gathers into bufn (HBM latency hides under kc4..7)
        #pragma unroll
        for (int it = 0; it < 4; ++it) {
            int s15 = l15 ^ ((it * 2 + rsub) & 7);
            gload_lds16(zb + (ival[it] << 7) + (s15 << 3),
                        bufn + ((w * 8 + it * 2) << 8));
        }
        asm volatile("" ::: "memory");  // pin: tail idx loads stay AFTER gathers

        #pragma unroll
        for (int kc = 4; kc < 8; ++kc) {
            bf16x8 a[4];
            #pragma unroll
            for (int i = 0; i < 4; ++i)
                a[i] = *(const bf16x8*)&bufc[((l15 + 16 * i) << 8) + ((((kc << 2) + l4) ^ swz) << 3)];
            #pragma unroll
            for (int i = 0; i < 4; ++i)
                #pragma unroll
                for (int j = 0; j < 4; ++j)
                    acc[i][j] = __builtin_amdgcn_mfma_f32_16x16x32_bf16(
                        a[i], *(const bf16x8*)&breg[j][kc], acc[i][j], 0, 0, 0);
        }

        // tail: idx for tile t+2G (consumed by NEXT iter's gather-issue)
        {
            int tt = t + 2 * G;
            #pragma unroll
            for (int it = 0; it < 4; ++it) {
                int e = tt * 64 + w * 8 + it * 2 + rsub;
                e = (e < E) ? e : (E - 1);
                ival[it] = ei[side * E + e];
            }
        }

        // fused epilogue: h = relu(acc + b1); y = sum_h h * W2[h]
        float y[4][4];
        #pragma unroll
        for (int i = 0; i < 4; i++)
            #pragma unroll
            for (int r = 0; r < 4; r++) y[i][r] = 0.f;

        #pragma unroll
        for (int j = 0; j < 4; j++) {
            #pragma unroll
            for (int i = 0; i < 4; i++)
                #pragma unroll
                for (int r = 0; r < 4; r++) {
                    float hv = acc[i][j][r] + b1v[j];
                    y[i][r] = fmaf(fmaxf(hv, 0.f), w2v[j], y[i][r]);
                }
        }

        // reduce over the 16 h-lanes (C layout: col = lane&15)
        #pragma unroll
        for (int i = 0; i < 4; i++)
            #pragma unroll
            for (int r = 0; r < 4; r++) {
                float v = y[i][r];
                v += __shfl_xor(v, 1);
                v += __shfl_xor(v, 2);
                v += __shfl_xor(v, 4);
                v += __shfl_xor(v, 8);
                y[i][r] = v;
            }

        if (l15 == 0) {
            #pragma unroll
            for (int i = 0; i < 4; i++)
                #pragma unroll
                for (int r = 0; r < 4; r++) {
                    int m = i * 16 + l4 * 4 + r;   // C layout: row=(lane>>4)*4+reg
                    ldsY[w * 64 + m] = y[i][r];
                }
        }
        asm volatile("s_waitcnt lgkmcnt(0)" ::: "memory");
        __builtin_amdgcn_s_barrier();
        asm volatile("" ::: "memory");
        if (tid < 64) {
            int e = t * 64 + tid;
            if (e < E) {
                float v = b2v;
                #pragma unroll
                for (int k = 0; k < 8; ++k) v += ldsY[k * 64 + tid];
                out[e] = v;          // single writer; NEWEST vmem in queue
            }
        }

        cur ^= 1;
    }
}

extern "C" void kernel_launch(void* const* d_in, const int* in_sizes, int n_in,
                              void* d_out, int out_size, void* d_ws, size_t ws_size,
                              hipStream_t stream) {
    const float* z  = (const float*)d_in[0];
    const int*   ei = (const int*)d_in[1];
    const float* W1 = (const float*)d_in[2];
    const float* b1 = (const float*)d_in[3];
    const float* W2 = (const float*)d_in[4];
    const float* b2 = (const float*)d_in[5];
    float* out = (float*)d_out;

    const int E  = in_sizes[1] / 2;   // 500000
    const int NZ = in_sizes[0];       // 6400000 = N*D

    unsigned short* zb  = (unsigned short*)d_ws;       // 12.8 MB
    unsigned short* w1s = zb + NZ;                     // 256 KB (swizzled W1)

    prep_kernel<<<2048, 256, 0, stream>>>(z, W1, zb, w1s, NZ / 4);

    const int ntiles = (E + 63) / 64;                  // 7813
    int grid = ntiles < 512 ? ntiles : 512;            // persistent, ~15 tiles/block
    edge_mlp_kernel<<<grid, 512, 0, stream>>>(ei, zb, w1s, b1, W2, b2, out, E, ntiles);
}

// Round 3
// 212.752 us; speedup vs baseline: 1.0884x; 1.0884x over previous
//
#include <hip/hip_runtime.h>

// y[e] = W2 . relu(W1 . concat(z[src[e]], z[dst[e]]) + b1) + b2
// N=50000, D=128, H=512, E=500000. 131 GFLOP in GEMM1.
// R10: operand-swapped MFMA. R9's plateau: LDS pipe ~6.4K cyc/tile
// (3.0K A-reads + 3.0K ds_bpermute from 512 shfl_xor/tile) > MFMA 5.0K;
// SQ_LDS_BANK_CONFLICT == 16*E exactly, invariant across R7/R8/R9 ->
// it's the epilogue shuffle reduction, not the A-tile reads.
// Swap: mfma(W1_frag, edge_frag) -> C row=h, col=edge. Same w1s layout
// (A/B per-lane layouts symmetric), same LDS read addresses. h-reduce is
// now in-register (sum over j,r) + 2 shuffles (xor16,32) per edge-tile:
// bpermutes 64 -> 8 per wave. b1 folded into acc INIT (staged in LDS,
// f32x4 per j) to keep register demand ~neutral; w2 = 16 persistent regs.
// setprio(1) around MFMA clusters. Everything else (persistent blocks,
// B-in-regs, global_load_lds double-buffer, vmcnt(4) discipline,
// source-side XOR swizzle) unchanged from R9.

typedef __bf16 bf16x8 __attribute__((ext_vector_type(8)));
typedef float f32x4 __attribute__((ext_vector_type(4)));

__device__ __forceinline__ unsigned short f2b(float f) {
    unsigned int u = __float_as_uint(f);
    u = (u + 0x7fffu + ((u >> 16) & 1u)) >> 16;   // RNE
    return (unsigned short)u;
}

__device__ __forceinline__ void gload_lds16(const unsigned short* g, unsigned short* l) {
    __builtin_amdgcn_global_load_lds(
        (const __attribute__((address_space(1))) unsigned int*)g,
        (__attribute__((address_space(3))) unsigned int*)l, 16, 0, 0);
}

// zb: z as bf16 [N][128].  w1s: W1 swizzled to MFMA fragment order:
// w1s[(hblk*8 + kc)*512 + lane*8 + t] = bf16(W1[hblk*16 + (lane&15)][kc*32 + (lane>>4)*8 + t])
__global__ void prep_kernel(const float* __restrict__ z, const float* __restrict__ W1,
                            unsigned short* __restrict__ zb, unsigned short* __restrict__ w1s,
                            int nz4) {
    int stride = gridDim.x * blockDim.x;
    const int nw = 256 * 64;   // (hblk*8+kc) x lane
    const int total = nz4 + nw;
    for (int idx = blockIdx.x * blockDim.x + threadIdx.x; idx < total; idx += stride) {
        if (idx < nz4) {
            float4 v = ((const float4*)z)[idx];
            ushort4 o;
            o.x = f2b(v.x); o.y = f2b(v.y); o.z = f2b(v.z); o.w = f2b(v.w);
            ((ushort4*)zb)[idx] = o;
        } else {
            int u = idx - nz4;            // 0..16383
            int lane = u & 63;
            int blk  = u >> 6;            // hblk*8 + kc
            int h  = (blk >> 3) * 16 + (lane & 15);
            int kb = (blk & 7) * 32 + (lane >> 4) * 8;
            const float* src = W1 + h * 256 + kb;
            ushort4 o0, o1;
            float4 v0 = *(const float4*)(src);
            float4 v1 = *(const float4*)(src + 4);
            o0.x = f2b(v0.x); o0.y = f2b(v0.y); o0.z = f2b(v0.z); o0.w = f2b(v0.w);
            o1.x = f2b(v1.x); o1.y = f2b(v1.y); o1.z = f2b(v1.z); o1.w = f2b(v1.w);
            ushort4* dst = (ushort4*)(w1s + u * 8);
            dst[0] = o0; dst[1] = o1;
        }
    }
}

__global__ __launch_bounds__(512, 2)
void edge_mlp_kernel(const int* __restrict__ ei, const unsigned short* __restrict__ zb,
                     const unsigned short* __restrict__ w1s,
                     const float* __restrict__ b1, const float* __restrict__ W2,
                     const float* __restrict__ b2p, float* __restrict__ out,
                     int E, int ntiles) {
    // linear (unpadded) A tiles, double-buffered; XOR-swizzled 16B slots
    __shared__ unsigned short ldsA[2][64 * 256];  // 2 x 32 KB
    __shared__ float ldsY[512];                   // 2 KB partial-y exchange
    __shared__ float ldsB1[512];                  // 2 KB staged b1

    const int tid  = threadIdx.x;
    const int lane = tid & 63;
    const int w    = tid >> 6;        // 0..7 : 64-h slice of H=512
    const int l15  = lane & 15;
    const int l4   = lane >> 4;
    const int G    = gridDim.x;

    const int t0 = blockIdx.x;
    if (t0 >= ntiles) return;

    ldsB1[tid] = b1[tid];             // wave-local consumers (w*64.. span)

    // ---- persistent W1: wave w holds hblk w*4..w*4+3, full K, in regs ----
    uint4 breg[4][8];                 // 128 regs
    #pragma unroll
    for (int j = 0; j < 4; ++j)
        #pragma unroll
        for (int kc = 0; kc < 8; ++kc)
            breg[j][kc] = *(const uint4*)(w1s + (((w * 4 + j) * 8 + kc) << 9) + lane * 8);

    // w2 per lane: h = w*64 + j*16 + l4*4 + r  -> f32x4 per j (16 regs)
    f32x4 w2v[4];
    #pragma unroll
    for (int j = 0; j < 4; ++j)
        w2v[j] = *(const f32x4*)&W2[w * 64 + j * 16 + l4 * 4];
    const float b2v = b2p[0];

    // gather geometry: instr it covers rows m0=w*8+it*2 (+rsub), lane L writes
    // LDS (row, slot'=L&31); that slot' holds global k-slot s = slot'^(row&7).
    const int side = (lane >> 4) & 1;
    const int rsub = lane >> 5;
    const int swz  = l15 & 7;         // read-side XOR: row&7 == l15&7

    asm volatile("s_waitcnt vmcnt(0)" ::: "memory");   // drain preloads: clean vmcnt base

    // ---- prologue: idx(T0) -> gather(T0) -> idx(T1) ----
    int ival[4];
    #pragma unroll
    for (int it = 0; it < 4; ++it) {
        int e = t0 * 64 + w * 8 + it * 2 + rsub;
        e = (e < E) ? e : (E - 1);
        ival[it] = ei[side * E + e];
    }
    #pragma unroll
    for (int it = 0; it < 4; ++it) {   // compiler waits ival before addr use
        int s15 = l15 ^ ((it * 2 + rsub) & 7);
        gload_lds16(zb + (ival[it] << 7) + (s15 << 3),
                    &ldsA[0][(w * 8 + it * 2) << 8]);
    }
    asm volatile("" ::: "memory");     // pin: idx(T1) must stay AFTER gathers
    {
        int t1 = t0 + G;
        #pragma unroll
        for (int it = 0; it < 4; ++it) {
            int e = t1 * 64 + w * 8 + it * 2 + rsub;
            e = (e < E) ? e : (E - 1);
            ival[it] = ei[side * E + e];
        }
    }

    int cur = 0;
    for (int t = t0; t < ntiles; t += G) {
        // wait own 4 gathers (oldest in queue; idx/store are newer), rendezvous
        asm volatile("s_waitcnt vmcnt(4)" ::: "memory");
        __builtin_amdgcn_s_barrier();
        asm volatile("" ::: "memory");

        const unsigned short* bufc = &ldsA[cur][0];
        unsigned short* bufn = &ldsA[cur ^ 1][0];

        // acc init = b1 (so acc ends as W1.x + b1); C row=h, col=edge
        f32x4 acc[4][4];                  // [edge-tile i][h-tile j]
        {
            f32x4 b1t[4];
            #pragma unroll
            for (int j = 0; j < 4; ++j)
                b1t[j] = *(const f32x4*)&ldsB1[w * 64 + j * 16 + l4 * 4];
            #pragma unroll
            for (int i = 0; i < 4; i++)
                #pragma unroll
                for (int j = 0; j < 4; j++) acc[i][j] = b1t[j];
        }

        __builtin_amdgcn_s_setprio(1);
        #pragma unroll
        for (int kc = 0; kc < 4; ++kc) {
            bf16x8 a[4];
            #pragma unroll
            for (int i = 0; i < 4; ++i)
                a[i] = *(const bf16x8*)&bufc[((l15 + 16 * i) << 8) + ((((kc << 2) + l4) ^ swz) << 3)];
            #pragma unroll
            for (int i = 0; i < 4; ++i)
                #pragma unroll
                for (int j = 0; j < 4; ++j)
                    acc[i][j] = __builtin_amdgcn_mfma_f32_16x16x32_bf16(
                        *(const bf16x8*)&breg[j][kc], a[i], acc[i][j], 0, 0, 0);
        }
        __builtin_amdgcn_s_setprio(0);

        // issue next tile's gathers into bufn (HBM latency hides under kc4..7)
        #pragma unroll
        for (int it = 0; it < 4; ++it) {
            int s15 = l15 ^ ((it * 2 + rsub) & 7);
            gload_lds16(zb + (ival[it] << 7) + (s15 << 3),
                        bufn + ((w * 8 + it * 2) << 8));
        }
        asm volatile("" ::: "memory");  // pin: tail idx loads stay AFTER gathers

        __builtin_amdgcn_s_setprio(1);
        #pragma unroll
        for (int kc = 4; kc < 8; ++kc) {
            bf16x8 a[4];
            #pragma unroll
            for (int i = 0; i < 4; ++i)
                a[i] = *(const bf16x8*)&bufc[((l15 + 16 * i) << 8) + ((((kc << 2) + l4) ^ swz) << 3)];
            #pragma unroll
            for (int i = 0; i < 4; ++i)
                #pragma unroll
                for (int j = 0; j < 4; ++j)
                    acc[i][j] = __builtin_amdgcn_mfma_f32_16x16x32_bf16(
                        *(const bf16x8*)&breg[j][kc], a[i], acc[i][j], 0, 0, 0);
        }
        __builtin_amdgcn_s_setprio(0);

        // tail: idx for tile t+2G (consumed by NEXT iter's gather-issue)
        {
            int tt = t + 2 * G;
            #pragma unroll
            for (int it = 0; it < 4; ++it) {
                int e = tt * 64 + w * 8 + it * 2 + rsub;
                e = (e < E) ? e : (E - 1);
                ival[it] = ei[side * E + e];
            }
        }

        // epilogue: y[e] = sum_h relu(acc) * w2.  h-sum: in-reg over (j,r),
        // then 2 shuffles across the 4 l4 row-groups.
        #pragma unroll
        for (int i = 0; i < 4; i++) {
            float s = 0.f;
            #pragma unroll
            for (int j = 0; j < 4; j++)
                #pragma unroll
                for (int r = 0; r < 4; r++)
                    s = fmaf(fmaxf(acc[i][j][r], 0.f), w2v[j][r], s);
            s += __shfl_xor(s, 16);
            s += __shfl_xor(s, 32);
            if (l4 == 0) ldsY[w * 64 + i * 16 + l15] = s;
        }
        asm volatile("s_waitcnt lgkmcnt(0)" ::: "memory");
        __builtin_amdgcn_s_barrier();
        asm volatile("" ::: "memory");
        if (tid < 64) {
            int e = t * 64 + tid;
            if (e < E) {
                float v = b2v;
                #pragma unroll
                for (int k = 0; k < 8; ++k) v += ldsY[k * 64 + tid];
                out[e] = v;          // single writer; NEWEST vmem in queue
            }
        }

        cur ^= 1;
    }
}

extern "C" void kernel_launch(void* const* d_in, const int* in_sizes, int n_in,
                              void* d_out, int out_size, void* d_ws, size_t ws_size,
                              hipStream_t stream) {
    const float* z  = (const float*)d_in[0];
    const int*   ei = (const int*)d_in[1];
    const float* W1 = (const float*)d_in[2];
    const float* b1 = (const float*)d_in[3];
    const float* W2 = (const float*)d_in[4];
    const float* b2 = (const float*)d_in[5];
    float* out = (float*)d_out;

    const int E  = in_sizes[1] / 2;   // 500000
    const int NZ = in_sizes[0];       // 6400000 = N*D

    unsigned short* zb  = (unsigned short*)d_ws;       // 12.8 MB
    unsigned short* w1s = zb + NZ;                     // 256 KB (swizzled W1)

    prep_kernel<<<2048, 256, 0, stream>>>(z, W1, zb, w1s, NZ / 4);

    const int ntiles = (E + 63) / 64;                  // 7813
    int grid = ntiles < 512 ? ntiles : 512;            // persistent, ~15 tiles/block
    edge_mlp_kernel<<<grid, 512, 0, stream>>>(ei, zb, w1s, b1, W2, b2, out, E, ntiles);
}